// Round 3
// baseline (323.438 us; speedup 1.0000x reference)
//
#include <hip/hip_runtime.h>

// ---------------------------------------------------------------------------
// WaveSubsystem fused:
//   out = tanh(c@W_mod + b_mod) * (w @ M) + [c z]@W_B + b_B
//   M^T = diag(tanh(A_diag)*0.9) + A_U@A_V^T   (tiny GEMM, bf16)
// Round 9: fused_main ported to the m201-style pipelined schedule:
//   - 256x128 tile, 8 waves (4Mx2N, 64x64 each), BK=64, NT=96 linearized
//   - TRIPLE-buffered LDS (slot t%3, 144 KB): tile t+2's stages target a
//     slot last read at tile t-1 -> stage issues get ~1.5 tile-periods of
//     latency cover (round-1's double-buffer gave only ~1/4 period)
//   - 2 phases/tile, each {8 frag ds_reads; 3 stage issues; barrier;
//     setprio(1); 16 MFMA; setprio(0); barrier} -> wave role-split
//   - ONE counted vmcnt per tile (vmcnt(6) = t+2's 6 loads stay in flight,
//     everything older landed -> tile t+1 guaranteed ready). Never 0.
//   - XCD swizzle kept (FETCH 214->123 MB in round 1).
// prep_gemm: grid-stride fat blocks (28928 -> 3328 blocks) to kill
// per-block dispatch overhead; GEMM blocks first (overlap).
// ---------------------------------------------------------------------------

#define DEV __device__ __forceinline__

typedef __bf16 v8bf __attribute__((ext_vector_type(8)));
typedef __bf16 v4bf __attribute__((ext_vector_type(4)));
typedef float  v4f  __attribute__((ext_vector_type(4)));

typedef __attribute__((address_space(1))) const unsigned int* as1_cuint_ptr;
typedef __attribute__((address_space(3))) unsigned int*       as3_uint_ptr;

DEV void async16(const void* g, void* l) {
  __builtin_amdgcn_global_load_lds(
      (as1_cuint_ptr)(unsigned long long)g,
      (as3_uint_ptr)(unsigned long long)l,
      16, 0, 0);
}

DEV float tanh_fast(float x) {
  x = fminf(15.f, fmaxf(-15.f, x));
  float e = __expf(2.f * x);
  return (e - 1.f) / (e + 1.f);
}

// ----------------------- merged prep + Mt kernel ---------------------------
// blocks [0,256):        Mt = AU@AV^T + diag(tanh(A_diag)*0.9) (fp32 in)
// blocks [256,2304):     grid-stride fp32->bf16 convert of w,z,c (10 units)
// blocks [2304,3328):    grid-stride transpose+convert Wmod,WB (8 units)
__global__ __launch_bounds__(256, 2) void prep_gemm(
    const float* __restrict__ w, const float* __restrict__ z,
    const float* __restrict__ c, const float* __restrict__ au,
    const float* __restrict__ av, const float* __restrict__ Wmod,
    const float* __restrict__ WB, const float* __restrict__ A_diag,
    __bf16* __restrict__ wb, __bf16* __restrict__ zb, __bf16* __restrict__ cb,
    __bf16* __restrict__ Wmodt, __bf16* __restrict__ WBt,
    __bf16* __restrict__ Mt) {
  __shared__ __align__(16) char smem[16384];
  int b = blockIdx.x;

  if (b < 256) {
    // ---- Mt builder GEMM: 128x128 tile, K=512, BK=32 ----
    __bf16* As = (__bf16*)smem;             // [128][32] bf16, 8 KB
    __bf16* Bs = (__bf16*)(smem + 8192);    // [128][32] bf16, 8 KB
    const int tid = threadIdx.x, lane = tid & 63, wid = tid >> 6;
    const int wm = wid >> 1, wn = wid & 1, l16 = lane & 15, quad = lane >> 4;
    const int m0 = (b >> 4) * 128, n0 = (b & 15) * 128;
    const int qs = quad ^ ((l16 >> 1) & 3);
    const int row = tid >> 1, sp = (tid & 1) * 2;

    v4f acc[4][4];
#pragma unroll
    for (int i = 0; i < 4; ++i)
#pragma unroll
      for (int j = 0; j < 4; ++j) { v4f zz = {0, 0, 0, 0}; acc[i][j] = zz; }

    for (int k0 = 0; k0 < 512; k0 += 32) {
      __syncthreads();
#pragma unroll
      for (int ss = 0; ss < 2; ++ss) {
        const int s = sp + ss;
        const int gk = (s ^ ((row >> 1) & 3)) * 8;
        const float* pa = au + (size_t)(m0 + row) * 512 + k0 + gk;
        const float* pb = av + (size_t)(n0 + row) * 512 + k0 + gk;
        float4 a0 = *reinterpret_cast<const float4*>(pa);
        float4 a1 = *reinterpret_cast<const float4*>(pa + 4);
        float4 b0 = *reinterpret_cast<const float4*>(pb);
        float4 b1 = *reinterpret_cast<const float4*>(pb + 4);
        v8bf va, vb;
        va[0] = (__bf16)a0.x; va[1] = (__bf16)a0.y;
        va[2] = (__bf16)a0.z; va[3] = (__bf16)a0.w;
        va[4] = (__bf16)a1.x; va[5] = (__bf16)a1.y;
        va[6] = (__bf16)a1.z; va[7] = (__bf16)a1.w;
        vb[0] = (__bf16)b0.x; vb[1] = (__bf16)b0.y;
        vb[2] = (__bf16)b0.z; vb[3] = (__bf16)b0.w;
        vb[4] = (__bf16)b1.x; vb[5] = (__bf16)b1.y;
        vb[6] = (__bf16)b1.z; vb[7] = (__bf16)b1.w;
        *reinterpret_cast<v8bf*>(&As[row * 32 + s * 8]) = va;
        *reinterpret_cast<v8bf*>(&Bs[row * 32 + s * 8]) = vb;
      }
      __syncthreads();
      const v8bf* Ap = reinterpret_cast<const v8bf*>(As);
      const v8bf* Bp = reinterpret_cast<const v8bf*>(Bs);
      v8bf a[4], bb[4];
#pragma unroll
      for (int i = 0; i < 4; ++i) a[i] = Ap[(wm * 64 + i * 16 + l16) * 4 + qs];
#pragma unroll
      for (int j = 0; j < 4; ++j) bb[j] = Bp[(wn * 64 + j * 16 + l16) * 4 + qs];
#pragma unroll
      for (int i = 0; i < 4; ++i)
#pragma unroll
        for (int j = 0; j < 4; ++j)
          acc[i][j] = __builtin_amdgcn_mfma_f32_16x16x32_bf16(a[i], bb[j],
                                                              acc[i][j], 0, 0, 0);
    }

    const int mBase = m0 + wm * 64 + quad * 4;
    const int nBase = n0 + wn * 64 + l16;
#pragma unroll
    for (int j = 0; j < 4; ++j) {
      const int n = nBase + j * 16;
#pragma unroll
      for (int i = 0; i < 4; ++i)
#pragma unroll
        for (int r = 0; r < 4; ++r) {
          const int m = mBase + i * 16 + r;
          float v = acc[i][j][r];
          if (m == n) v += tanh_fast(A_diag[m]) * 0.9f;
          Mt[(size_t)m * 2048 + n] = (__bf16)v;
        }
    }
    return;
  }

  b -= 256;
  if (b < 2048) {
    // ---- fp32 -> bf16 conversion, grid-stride over 20480 units ----
    for (int u = b; u < 20480; u += 2048) {
      const float* src; __bf16* dst; int off;
      if (u < 8192)       { src = w; dst = wb; off = u; }
      else if (u < 16384) { src = z; dst = zb; off = u - 8192; }
      else                { src = c; dst = cb; off = u - 16384; }
      size_t i = (size_t)off * 1024 + (size_t)threadIdx.x * 4;
      float4 v = *reinterpret_cast<const float4*>(src + i);
      v4bf o;
      o.x = (__bf16)v.x; o.y = (__bf16)v.y;
      o.z = (__bf16)v.z; o.w = (__bf16)v.w;
      *reinterpret_cast<v4bf*>(dst + i) = o;
    }
    return;
  }

  b -= 2048;
  // ---- transpose + convert: Wmod -> Wmodt, WB -> WBt (grid-stride) ----
  float (*t)[33] = (float(*)[33])smem;  // 32x33 fp32
  const int tx = threadIdx.x & 31, ty = threadIdx.x >> 5;
  const int orow = threadIdx.x >> 3;       // 0..31 output row within tile
  const int oc   = (threadIdx.x & 7) * 4;  // 0..28 output col group
  for (int u = b; u < 8192; u += 1024) {
    const float* src; __bf16* dst; int R, uu = u;
    if (uu < 2048) { src = Wmod; dst = Wmodt; R = 1024; }
    else           { uu -= 2048; src = WB; dst = WBt; R = 3072; }
    const int c0 = (uu & 63) * 32, r0 = (uu >> 6) * 32;
    const int C = 2048;
    __syncthreads();  // previous iteration's reads of t[] complete
#pragma unroll
    for (int rr = 0; rr < 32; rr += 8)
      t[ty + rr][tx] = src[(size_t)(r0 + ty + rr) * C + c0 + tx];
    __syncthreads();
    v4bf o;
    o.x = (__bf16)t[oc + 0][orow];
    o.y = (__bf16)t[oc + 1][orow];
    o.z = (__bf16)t[oc + 2][orow];
    o.w = (__bf16)t[oc + 3][orow];
    *reinterpret_cast<v4bf*>(&dst[(size_t)(c0 + orow) * R + r0 + oc]) = o;
  }
}

// ---------------------- fused main kernel ----------------------------------
// m201-style schedule: 256x128 tile, 8 waves, BK=64, triple-buffered LDS,
// 2 phases/tile with per-phase barrier pairs, counted vmcnt once per tile.
__global__ __launch_bounds__(512, 2) void fused_main(
    const __bf16* __restrict__ c, const __bf16* __restrict__ z,
    const __bf16* __restrict__ w, const __bf16* __restrict__ Wmodt,
    const __bf16* __restrict__ Mt, const __bf16* __restrict__ WBt,
    const float* __restrict__ b_mod, const float* __restrict__ b_B,
    float* __restrict__ out) {
  constexpr int DC = 1024, DW = 2048, KB3 = 3072;
  constexpr int ATE = 256 * 64;  // A tile elems (32 KB)
  constexpr int BTE = 128 * 64;  // B tile elems (16 KB)
  constexpr int NT = 96;         // 16 (phase A) + 32 (phase B) + 48 (phase C)
  __shared__ __align__(16) __bf16 As[3 * ATE];  // 96 KB
  __shared__ __align__(16) __bf16 Bs[3 * BTE];  // 48 KB

  const int tid = threadIdx.x, lane = tid & 63, wid = tid >> 6;
  const int wm = wid >> 1, wn = wid & 1;        // 4M x 2N wave grid
  const int l16 = lane & 15, quad = lane >> 4, l8 = l16 & 7;
  const int s8 = tid & 7, rowi = tid >> 3;      // staging: 8 thr/row, 64 rows
  const int gks = ((s8 ^ (rowi & 7)) << 3);     // pre-swizzled global k elem

  // bijective XCD swizzle: 256 blocks = 8 XCDs x 32; each XCD covers 2 full
  // m-rows (A panels L2-resident; measured FETCH 214->123 MB).
  const int flat = blockIdx.y * 16 + blockIdx.x;
  const int swz = (flat & 7) * 32 + (flat >> 3);
  const int m0 = (swz >> 4) * 256;   // batch tile
  const int n0 = (swz & 15) * 128;   // d_w tile

  const int nBase = n0 + wn * 64 + l16;
  float bmodr[4], bBr[4];
#pragma unroll
  for (int j = 0; j < 4; ++j) {
    bmodr[j] = b_mod[nBase + j * 16];
    bBr[j]   = b_B[nBase + j * 16];
  }

  auto resolve = [&](int T, const __bf16*& gA, int& lda, int& kA,
                     const __bf16*& gB, int& ldb, int& kB) {
    if (T < 16)      { gA = c; lda = DC; kA = T << 6;        gB = Wmodt; ldb = DC;  kB = T << 6; }
    else if (T < 48) { gA = w; lda = DW; kA = (T - 16) << 6; gB = Mt;    ldb = DW;  kB = (T - 16) << 6; }
    else if (T < 64) { gA = c; lda = DC; kA = (T - 48) << 6; gB = WBt;   ldb = KB3; kB = (T - 48) << 6; }
    else             { gA = z; lda = DW; kA = (T - 64) << 6; gB = WBt;   ldb = KB3; kB = DC + ((T - 64) << 6); }
  };

  // stage A-load instrs [q0, q0+qn) of tile T (each covers 64 rows)
  auto stageA = [&](int T, int q0, int qn) {
    const __bf16* gA; const __bf16* gB; int lda, ldb, kA, kB;
    resolve(T, gA, lda, kA, gB, ldb, kB);
    __bf16* Ab = &As[(T % 3) * ATE];
#pragma unroll
    for (int q = 0; q < 4; ++q) {
      if (q < q0 || q >= q0 + qn) continue;
      const int row = q * 64 + rowi;
      async16((const void*)(gA + (size_t)(m0 + row) * lda + kA + gks),
              (void*)&Ab[row * 64 + s8 * 8]);
    }
  };
  auto stageB = [&](int T) {
    const __bf16* gA; const __bf16* gB; int lda, ldb, kA, kB;
    resolve(T, gA, lda, kA, gB, ldb, kB);
    __bf16* Bb = &Bs[(T % 3) * BTE];
#pragma unroll
    for (int q = 0; q < 2; ++q) {
      const int row = q * 64 + rowi;
      async16((const void*)(gB + (size_t)(n0 + row) * ldb + kB + gks),
              (void*)&Bb[row * 64 + s8 * 8]);
    }
  };

  v4f acc[4][4];
#pragma unroll
  for (int i = 0; i < 4; ++i)
#pragma unroll
    for (int j = 0; j < 4; ++j) { v4f zz = {0, 0, 0, 0}; acc[i][j] = zz; }
  v4bf mod_b[4][4];  // modulation as bf16 (saves 32 VGPRs)

  // prologue: stage tiles 0 and 1 (12 loads); wait tile 0 (6 newer fly)
  stageA(0, 0, 4); stageB(0);
  stageA(1, 0, 4); stageB(1);
  asm volatile("s_waitcnt vmcnt(6)" ::: "memory");
  __builtin_amdgcn_s_barrier();
  asm volatile("" ::: "memory");

  for (int t = 0; t < NT; ++t) {
    const v8bf* Ap = reinterpret_cast<const v8bf*>(&As[(t % 3) * ATE]);
    const v8bf* Bp = reinterpret_cast<const v8bf*>(&Bs[(t % 3) * BTE]);
    const bool pre = (t + 2 < NT);

    // ---- phase 0: frag reads (ks=0) | stage 3 | bar | 16 MFMA | bar ----
    v8bf a0[4], b0[4];
#pragma unroll
    for (int i = 0; i < 4; ++i)
      a0[i] = Ap[(wm * 64 + i * 16 + l16) * 8 + (quad ^ l8)];
#pragma unroll
    for (int j = 0; j < 4; ++j)
      b0[j] = Bp[(wn * 64 + j * 16 + l16) * 8 + (quad ^ l8)];
    if (pre) stageA(t + 2, 0, 3);
    asm volatile("" ::: "memory");
    __builtin_amdgcn_s_barrier();
    __builtin_amdgcn_s_setprio(1);
#pragma unroll
    for (int i = 0; i < 4; ++i)
#pragma unroll
      for (int j = 0; j < 4; ++j)
        acc[i][j] = __builtin_amdgcn_mfma_f32_16x16x32_bf16(a0[i], b0[j],
                                                            acc[i][j], 0, 0, 0);
    __builtin_amdgcn_s_setprio(0);
    asm volatile("" ::: "memory");
    __builtin_amdgcn_s_barrier();

    // ---- phase 1: frag reads (ks=1) | stage 3 | bar | 16 MFMA | vm | bar --
    v8bf a1[4], b1[4];
#pragma unroll
    for (int i = 0; i < 4; ++i)
      a1[i] = Ap[(wm * 64 + i * 16 + l16) * 8 + ((4 + quad) ^ l8)];
#pragma unroll
    for (int j = 0; j < 4; ++j)
      b1[j] = Bp[(wn * 64 + j * 16 + l16) * 8 + ((4 + quad) ^ l8)];
    if (pre) { stageA(t + 2, 3, 1); stageB(t + 2); }
    asm volatile("" ::: "memory");
    __builtin_amdgcn_s_barrier();
    __builtin_amdgcn_s_setprio(1);
#pragma unroll
    for (int i = 0; i < 4; ++i)
#pragma unroll
      for (int j = 0; j < 4; ++j)
        acc[i][j] = __builtin_amdgcn_mfma_f32_16x16x32_bf16(a1[i], b1[j],
                                                            acc[i][j], 0, 0, 0);
    __builtin_amdgcn_s_setprio(0);
    // counted wait: t+2's 6 loads stay in flight; all older (t+1's) landed.
    if (pre) asm volatile("s_waitcnt vmcnt(6)" ::: "memory");
    else     asm volatile("s_waitcnt vmcnt(0)" ::: "memory");
    __builtin_amdgcn_s_barrier();
    asm volatile("" ::: "memory");

    if (t == 15) {  // end of GEMM phase A: mod = tanh(acc + b_mod); acc = 0
#pragma unroll
      for (int i = 0; i < 4; ++i)
#pragma unroll
        for (int j = 0; j < 4; ++j) {
          v4bf mb;
#pragma unroll
          for (int r = 0; r < 4; ++r)
            mb[r] = (__bf16)tanh_fast(acc[i][j][r] + bmodr[j]);
          mod_b[i][j] = mb;
          v4f zz = {0, 0, 0, 0};
          acc[i][j] = zz;
        }
    } else if (t == 47) {  // end of GEMM phase B: acc *= mod
#pragma unroll
      for (int i = 0; i < 4; ++i)
#pragma unroll
        for (int j = 0; j < 4; ++j)
#pragma unroll
          for (int r = 0; r < 4; ++r)
            acc[i][j][r] *= (float)mod_b[i][j][r];
    }
  }

  // ---- epilogue ----
  const int mBase = m0 + wm * 64 + quad * 4;
#pragma unroll
  for (int j = 0; j < 4; ++j) {
    const int n = nBase + j * 16;
#pragma unroll
    for (int i = 0; i < 4; ++i)
#pragma unroll
      for (int r = 0; r < 4; ++r)
        out[(size_t)(mBase + i * 16 + r) * DW + n] = acc[i][j][r] + bBr[j];
  }
}

// ------------------------------ launch -------------------------------------

extern "C" void kernel_launch(void* const* d_in, const int* in_sizes, int n_in,
                              void* d_out, int out_size, void* d_ws,
                              size_t ws_size, hipStream_t stream) {
  const float* w_prev = (const float*)d_in[0];
  const float* z_t    = (const float*)d_in[1];
  const float* c_t    = (const float*)d_in[2];
  const float* A_diag = (const float*)d_in[3];
  const float* A_U    = (const float*)d_in[4];
  const float* A_V    = (const float*)d_in[5];
  const float* W_mod  = (const float*)d_in[6];
  const float* b_mod  = (const float*)d_in[7];
  const float* W_B    = (const float*)d_in[8];
  const float* b_B    = (const float*)d_in[9];

  const size_t MB = 1ull << 20;
  char* ws = (char*)d_ws;
  __bf16* w_bf  = (__bf16*)(ws + 0);        // 16 MB
  __bf16* z_bf  = (__bf16*)(ws + 16 * MB);  // 16 MB
  __bf16* c_bf  = (__bf16*)(ws + 32 * MB);  //  8 MB
  __bf16* Wmodt = (__bf16*)(ws + 40 * MB);  //  4 MB  [2048][1024]
  __bf16* WBt   = (__bf16*)(ws + 44 * MB);  // 12 MB  [2048][3072]
  __bf16* Mt    = (__bf16*)(ws + 56 * MB);  //  8 MB  [2048][2048]

  prep_gemm<<<3328, 256, 0, stream>>>(w_prev, z_t, c_t, A_U, A_V, W_mod, W_B,
                                      A_diag, w_bf, z_bf, c_bf, Wmodt, WBt,
                                      Mt);

  fused_main<<<dim3(16, 16), 512, 0, stream>>>(
      c_bf, z_bf, w_bf, Wmodt, Mt, WBt, b_mod, b_B, (float*)d_out);
}

// Round 4
// 281.519 us; speedup vs baseline: 1.1489x; 1.1489x over previous
//
#include <hip/hip_runtime.h>

// ---------------------------------------------------------------------------
// WaveSubsystem fused:
//   out = tanh(c@W_mod + b_mod) * (w @ M) + [c z]@W_B + b_B
//   M^T = diag(tanh(A_diag)*0.9) + A_U@A_V^T   (tiny GEMM, bf16)
// Round 10: consolidation. fused_main = proven round-6 structure (BK=128,
// 64 KB LDS, 2 blocks/CU, 912 TF, 110 us measured). Two pipelined rewrites
// (r7: coarse split, 142 us; r9: 2-phase m201-ish port, 161 us) both
// regressed -- m114's implicit 2-blocks/CU wave overlap beats my explicit
// schedules; keeping the proven kernel. prep_gemm = round-9 grid-stride
// merged kernel (best non-fused time measured: 162 us vs 169/175).
// ---------------------------------------------------------------------------

#define DEV __device__ __forceinline__

typedef __bf16 v8bf __attribute__((ext_vector_type(8)));
typedef __bf16 v4bf __attribute__((ext_vector_type(4)));
typedef float  v4f  __attribute__((ext_vector_type(4)));

typedef __attribute__((address_space(1))) const unsigned int* as1_cuint_ptr;
typedef __attribute__((address_space(3))) unsigned int*       as3_uint_ptr;

DEV void async16(const void* g, void* l) {
  __builtin_amdgcn_global_load_lds(
      (as1_cuint_ptr)(unsigned long long)g,
      (as3_uint_ptr)(unsigned long long)l,
      16, 0, 0);
}

DEV float tanh_fast(float x) {
  x = fminf(15.f, fmaxf(-15.f, x));
  float e = __expf(2.f * x);
  return (e - 1.f) / (e + 1.f);
}

// ----------------------- merged prep + Mt kernel ---------------------------
// blocks [0,256):        Mt = AU@AV^T + diag(tanh(A_diag)*0.9) (fp32 in)
// blocks [256,2304):     grid-stride fp32->bf16 convert of w,z,c (10 units)
// blocks [2304,3328):    grid-stride transpose+convert Wmod,WB (8 units)
__global__ __launch_bounds__(256, 2) void prep_gemm(
    const float* __restrict__ w, const float* __restrict__ z,
    const float* __restrict__ c, const float* __restrict__ au,
    const float* __restrict__ av, const float* __restrict__ Wmod,
    const float* __restrict__ WB, const float* __restrict__ A_diag,
    __bf16* __restrict__ wb, __bf16* __restrict__ zb, __bf16* __restrict__ cb,
    __bf16* __restrict__ Wmodt, __bf16* __restrict__ WBt,
    __bf16* __restrict__ Mt) {
  __shared__ __align__(16) char smem[16384];
  int b = blockIdx.x;

  if (b < 256) {
    // ---- Mt builder GEMM: 128x128 tile, K=512, BK=32 ----
    __bf16* As = (__bf16*)smem;             // [128][32] bf16, 8 KB
    __bf16* Bs = (__bf16*)(smem + 8192);    // [128][32] bf16, 8 KB
    const int tid = threadIdx.x, lane = tid & 63, wid = tid >> 6;
    const int wm = wid >> 1, wn = wid & 1, l16 = lane & 15, quad = lane >> 4;
    const int m0 = (b >> 4) * 128, n0 = (b & 15) * 128;
    const int qs = quad ^ ((l16 >> 1) & 3);
    const int row = tid >> 1, sp = (tid & 1) * 2;

    v4f acc[4][4];
#pragma unroll
    for (int i = 0; i < 4; ++i)
#pragma unroll
      for (int j = 0; j < 4; ++j) { v4f zz = {0, 0, 0, 0}; acc[i][j] = zz; }

    for (int k0 = 0; k0 < 512; k0 += 32) {
      __syncthreads();
#pragma unroll
      for (int ss = 0; ss < 2; ++ss) {
        const int s = sp + ss;
        const int gk = (s ^ ((row >> 1) & 3)) * 8;
        const float* pa = au + (size_t)(m0 + row) * 512 + k0 + gk;
        const float* pb = av + (size_t)(n0 + row) * 512 + k0 + gk;
        float4 a0 = *reinterpret_cast<const float4*>(pa);
        float4 a1 = *reinterpret_cast<const float4*>(pa + 4);
        float4 b0 = *reinterpret_cast<const float4*>(pb);
        float4 b1 = *reinterpret_cast<const float4*>(pb + 4);
        v8bf va, vb;
        va[0] = (__bf16)a0.x; va[1] = (__bf16)a0.y;
        va[2] = (__bf16)a0.z; va[3] = (__bf16)a0.w;
        va[4] = (__bf16)a1.x; va[5] = (__bf16)a1.y;
        va[6] = (__bf16)a1.z; va[7] = (__bf16)a1.w;
        vb[0] = (__bf16)b0.x; vb[1] = (__bf16)b0.y;
        vb[2] = (__bf16)b0.z; vb[3] = (__bf16)b0.w;
        vb[4] = (__bf16)b1.x; vb[5] = (__bf16)b1.y;
        vb[6] = (__bf16)b1.z; vb[7] = (__bf16)b1.w;
        *reinterpret_cast<v8bf*>(&As[row * 32 + s * 8]) = va;
        *reinterpret_cast<v8bf*>(&Bs[row * 32 + s * 8]) = vb;
      }
      __syncthreads();
      const v8bf* Ap = reinterpret_cast<const v8bf*>(As);
      const v8bf* Bp = reinterpret_cast<const v8bf*>(Bs);
      v8bf a[4], bb[4];
#pragma unroll
      for (int i = 0; i < 4; ++i) a[i] = Ap[(wm * 64 + i * 16 + l16) * 4 + qs];
#pragma unroll
      for (int j = 0; j < 4; ++j) bb[j] = Bp[(wn * 64 + j * 16 + l16) * 4 + qs];
#pragma unroll
      for (int i = 0; i < 4; ++i)
#pragma unroll
        for (int j = 0; j < 4; ++j)
          acc[i][j] = __builtin_amdgcn_mfma_f32_16x16x32_bf16(a[i], bb[j],
                                                              acc[i][j], 0, 0, 0);
    }

    const int mBase = m0 + wm * 64 + quad * 4;
    const int nBase = n0 + wn * 64 + l16;
#pragma unroll
    for (int j = 0; j < 4; ++j) {
      const int n = nBase + j * 16;
#pragma unroll
      for (int i = 0; i < 4; ++i)
#pragma unroll
        for (int r = 0; r < 4; ++r) {
          const int m = mBase + i * 16 + r;
          float v = acc[i][j][r];
          if (m == n) v += tanh_fast(A_diag[m]) * 0.9f;
          Mt[(size_t)m * 2048 + n] = (__bf16)v;
        }
    }
    return;
  }

  b -= 256;
  if (b < 2048) {
    // ---- fp32 -> bf16 conversion, grid-stride over 20480 units ----
    for (int u = b; u < 20480; u += 2048) {
      const float* src; __bf16* dst; int off;
      if (u < 8192)       { src = w; dst = wb; off = u; }
      else if (u < 16384) { src = z; dst = zb; off = u - 8192; }
      else                { src = c; dst = cb; off = u - 16384; }
      size_t i = (size_t)off * 1024 + (size_t)threadIdx.x * 4;
      float4 v = *reinterpret_cast<const float4*>(src + i);
      v4bf o;
      o.x = (__bf16)v.x; o.y = (__bf16)v.y;
      o.z = (__bf16)v.z; o.w = (__bf16)v.w;
      *reinterpret_cast<v4bf*>(dst + i) = o;
    }
    return;
  }

  b -= 2048;
  // ---- transpose + convert: Wmod -> Wmodt, WB -> WBt (grid-stride) ----
  float (*t)[33] = (float(*)[33])smem;  // 32x33 fp32
  const int tx = threadIdx.x & 31, ty = threadIdx.x >> 5;
  const int orow = threadIdx.x >> 3;       // 0..31 output row within tile
  const int oc   = (threadIdx.x & 7) * 4;  // 0..28 output col group
  for (int u = b; u < 8192; u += 1024) {
    const float* src; __bf16* dst; int R, uu = u;
    if (uu < 2048) { src = Wmod; dst = Wmodt; R = 1024; }
    else           { uu -= 2048; src = WB; dst = WBt; R = 3072; }
    const int c0 = (uu & 63) * 32, r0 = (uu >> 6) * 32;
    const int C = 2048;
    __syncthreads();  // previous iteration's reads of t[] complete
#pragma unroll
    for (int rr = 0; rr < 32; rr += 8)
      t[ty + rr][tx] = src[(size_t)(r0 + ty + rr) * C + c0 + tx];
    __syncthreads();
    v4bf o;
    o.x = (__bf16)t[oc + 0][orow];
    o.y = (__bf16)t[oc + 1][orow];
    o.z = (__bf16)t[oc + 2][orow];
    o.w = (__bf16)t[oc + 3][orow];
    *reinterpret_cast<v4bf*>(&dst[(size_t)(c0 + orow) * R + r0 + oc]) = o;
  }
}

// ---------------------- fused main kernel ----------------------------------
// Proven round-6 structure: 128x128 tile, 4 waves (64x64 each), BK=128
// macro-steps, LDS 64 KB, 2 blocks/CU. 16-slot XOR swizzle: LDS slot j of
// row r holds global slot j^(r&15); read slot (s*4+quad)^l16.
__global__ __launch_bounds__(256, 2) void fused_main(
    const __bf16* __restrict__ c, const __bf16* __restrict__ z,
    const __bf16* __restrict__ w, const __bf16* __restrict__ Wmodt,
    const __bf16* __restrict__ Mt, const __bf16* __restrict__ WBt,
    const float* __restrict__ b_mod, const float* __restrict__ b_B,
    float* __restrict__ out) {
  constexpr int DC = 1024, DW = 2048, KB = 3072;
  __shared__ __align__(16) __bf16 As[128 * 128];  // 32 KB
  __shared__ __align__(16) __bf16 Bs[128 * 128];  // 32 KB

  const int tid = threadIdx.x, lane = tid & 63, wid = tid >> 6;
  const int wm = wid >> 1, wn = wid & 1, l16 = lane & 15, quad = lane >> 4;
  const int m0 = blockIdx.y * 128;  // batch
  const int n0 = blockIdx.x * 128;  // d_w
  const int r4  = lane >> 4;   // 0..3 row-within-instr
  const int s16 = lane & 15;   // LDS slot index

  v4f acc[4][4];
#pragma unroll
  for (int i = 0; i < 4; ++i)
#pragma unroll
    for (int j = 0; j < 4; ++j) { v4f zz = {0,0,0,0}; acc[i][j] = zz; }

  // one BK=128 macro-step: stage 128 rows x 128 k of A and B, then 4 MFMA
  // substeps. Staging: wave wid covers rows [wid*32, wid*32+32), 8 instrs x
  // 4 rows each; LDS slot s16 of row r gets global slot s16^(r&15).
  auto kstep = [&](const __bf16* gA, size_t lda, const __bf16* gB, size_t ldb,
                   int kA, int kB) {
    __syncthreads();
#pragma unroll
    for (int t = 0; t < 8; ++t) {
      const int row = wid * 32 + t * 4 + r4;
      const int gk = (s16 ^ (row & 15)) * 8;  // global k elem offset
      async16((const void*)(gA + (size_t)(m0 + row) * lda + kA + gk),
              (void*)&As[row * 128 + s16 * 8]);
      async16((const void*)(gB + (size_t)(n0 + row) * ldb + kB + gk),
              (void*)&Bs[row * 128 + s16 * 8]);
    }
    __syncthreads();
    const v8bf* Ap = reinterpret_cast<const v8bf*>(As);
    const v8bf* Bp = reinterpret_cast<const v8bf*>(Bs);
#pragma unroll
    for (int s = 0; s < 4; ++s) {
      const int rs = (s * 4 + quad) ^ l16;  // swizzled read slot
      v8bf a[4], b[4];
#pragma unroll
      for (int i = 0; i < 4; ++i)
        a[i] = Ap[(wm * 64 + i * 16 + l16) * 16 + rs];
#pragma unroll
      for (int j = 0; j < 4; ++j)
        b[j] = Bp[(wn * 64 + j * 16 + l16) * 16 + rs];
#pragma unroll
      for (int i = 0; i < 4; ++i)
#pragma unroll
        for (int j = 0; j < 4; ++j)
          acc[i][j] = __builtin_amdgcn_mfma_f32_16x16x32_bf16(
              a[i], b[j], acc[i][j], 0, 0, 0);
    }
  };

  const int nBase = n0 + wn * 64 + l16;

  // ---- phase A: mod = tanh(c @ Wmodt + b_mod) ----
  for (int k0 = 0; k0 < DC; k0 += 128) kstep(c, DC, Wmodt, DC, k0, k0);

  v4f mod_s[4][4];
#pragma unroll
  for (int j = 0; j < 4; ++j) {
    const float bn = b_mod[nBase + j * 16];
#pragma unroll
    for (int i = 0; i < 4; ++i) {
#pragma unroll
      for (int r = 0; r < 4; ++r)
        mod_s[i][j][r] = tanh_fast(acc[i][j][r] + bn);
      v4f zz = {0,0,0,0};
      acc[i][j] = zz;
    }
  }

  // ---- phase B: acc = w @ Mt ----
  for (int k0 = 0; k0 < DW; k0 += 128) kstep(w, DW, Mt, DW, k0, k0);

#pragma unroll
  for (int i = 0; i < 4; ++i)
#pragma unroll
    for (int j = 0; j < 4; ++j) acc[i][j] *= mod_s[i][j];

  // ---- phase C: acc += [c z] @ WBt ----
  for (int k0 = 0; k0 < DC; k0 += 128) kstep(c, DC, WBt, KB, k0, k0);
  for (int k0 = DC; k0 < KB; k0 += 128) kstep(z, DW, WBt, KB, k0 - DC, k0);

  // ---- epilogue ----
  const int mBase = m0 + wm * 64 + quad * 4;
#pragma unroll
  for (int j = 0; j < 4; ++j) {
    const int n = nBase + j * 16;
    const float bn = b_B[n];
#pragma unroll
    for (int i = 0; i < 4; ++i)
#pragma unroll
      for (int r = 0; r < 4; ++r) {
        const int m = mBase + i * 16 + r;
        out[(size_t)m * DW + n] = acc[i][j][r] + bn;
      }
  }
}

// ------------------------------ launch -------------------------------------

extern "C" void kernel_launch(void* const* d_in, const int* in_sizes, int n_in,
                              void* d_out, int out_size, void* d_ws,
                              size_t ws_size, hipStream_t stream) {
  const float* w_prev = (const float*)d_in[0];
  const float* z_t    = (const float*)d_in[1];
  const float* c_t    = (const float*)d_in[2];
  const float* A_diag = (const float*)d_in[3];
  const float* A_U    = (const float*)d_in[4];
  const float* A_V    = (const float*)d_in[5];
  const float* W_mod  = (const float*)d_in[6];
  const float* b_mod  = (const float*)d_in[7];
  const float* W_B    = (const float*)d_in[8];
  const float* b_B    = (const float*)d_in[9];

  constexpr int Bsz = 4096, DW = 2048;
  const size_t MB = 1ull << 20;
  char* ws = (char*)d_ws;
  __bf16* w_bf  = (__bf16*)(ws + 0);        // 16 MB
  __bf16* z_bf  = (__bf16*)(ws + 16 * MB);  // 16 MB
  __bf16* c_bf  = (__bf16*)(ws + 32 * MB);  //  8 MB
  __bf16* Wmodt = (__bf16*)(ws + 40 * MB);  //  4 MB  [2048][1024]
  __bf16* WBt   = (__bf16*)(ws + 44 * MB);  // 12 MB  [2048][3072]
  __bf16* Mt    = (__bf16*)(ws + 56 * MB);  //  8 MB  [2048][2048]

  prep_gemm<<<3328, 256, 0, stream>>>(w_prev, z_t, c_t, A_U, A_V, W_mod, W_B,
                                      A_diag, w_bf, z_bf, c_bf, Wmodt, WBt,
                                      Mt);

  fused_main<<<dim3(DW / 128, Bsz / 128), 256, 0, stream>>>(
      c_bf, z_bf, w_bf, Wmodt, Mt, WBt, b_mod, b_B, (float*)d_out);
}